// Round 1
// baseline (1595.063 us; speedup 1.0000x reference)
//
#include <hip/hip_runtime.h>
#include <float.h>

#define NS 1536
#define DD 64

// ws layout (float elements)
static const size_t OFF_A  = 0;                          // A = h_sat + b1: [1536][64]
static const size_t OFF_C2 = 98304;                      // C2 = h_uav transposed [16][1536][4]
static const size_t OFF_L  = 196608;                     // logits [1536][1536]
static const size_t OFF_AS = 196608 + (size_t)NS * NS;   // int assign [1536]
// top_idx (ushort, 1536*256 = 786432 B, rank-linear) ALIASES A/C2 (dead after kB).

// ---------------- Kernel A: first-layer projections ----------------
__global__ __launch_bounds__(64) void kA(const float* __restrict__ sat,
                                         const float* __restrict__ uav,
                                         const float* __restrict__ W1,
                                         const float* __restrict__ b1,
                                         float* __restrict__ A,
                                         float* __restrict__ C2) {
    const int row = blockIdx.x;
    const int d = threadIdx.x;
    float accA = b1[d];
    float accC = 0.f;
    const float* __restrict__ satr = sat + row * DD;
    const float* __restrict__ uavr = uav + row * DD;
#pragma unroll 8
    for (int k = 0; k < DD; ++k) {
        accA = fmaf(satr[k], W1[k * DD + d], accA);
        accC = fmaf(uavr[k], W1[(DD + k) * DD + d], accC);
    }
    A[row * DD + d] = accA;
    C2[((size_t)(d >> 2) * NS + row) * 4 + (d & 3)] = accC;
}

// ---------------- Kernel B: all-pairs logits ----------------
__global__ __launch_bounds__(256) void kB(const float* __restrict__ A,
                                          const float* __restrict__ C2,
                                          const float* __restrict__ W2,
                                          const float* __restrict__ b2,
                                          const float* __restrict__ W3,
                                          float* __restrict__ L) {
    const int lane = threadIdx.x & 63;
    const int wave = threadIdx.x >> 6;
    const int i = __builtin_amdgcn_readfirstlane(blockIdx.x * 4 + wave);
    const int jbase = blockIdx.y * 256;
    const float* __restrict__ Ar = A + (size_t)i * DD;

    float u[4][32];
#pragma unroll
    for (int o = 0; o < 32; ++o) {
        const float b = b2[o];
        u[0][o] = b; u[1][o] = b; u[2][o] = b; u[3][o] = b;
    }

    const float4* __restrict__ C2v = (const float4*)C2;

    for (int d4 = 0; d4 < 16; ++d4) {
        float c[4][4];
#pragma unroll
        for (int p = 0; p < 4; ++p) {
            const float4 t = C2v[(size_t)d4 * NS + jbase + p * 64 + lane];
            c[p][0] = t.x; c[p][1] = t.y; c[p][2] = t.z; c[p][3] = t.w;
        }
#pragma unroll
        for (int dd = 0; dd < 4; ++dd) {
            const float a = Ar[d4 * 4 + dd];
            const float v0 = fmaxf(a + c[0][dd], 0.f);
            const float v1 = fmaxf(a + c[1][dd], 0.f);
            const float v2 = fmaxf(a + c[2][dd], 0.f);
            const float v3 = fmaxf(a + c[3][dd], 0.f);
            const float* __restrict__ w2r = W2 + (d4 * 4 + dd) * 32;
#pragma unroll
            for (int o = 0; o < 32; ++o) {
                const float w = w2r[o];
                u[0][o] = fmaf(v0, w, u[0][o]);
                u[1][o] = fmaf(v1, w, u[1][o]);
                u[2][o] = fmaf(v2, w, u[2][o]);
                u[3][o] = fmaf(v3, w, u[3][o]);
            }
        }
    }

#pragma unroll
    for (int p = 0; p < 4; ++p) {
        float acc = 0.f;
#pragma unroll
        for (int o = 0; o < 32; ++o)
            acc = fmaf(fmaxf(u[p][o], 0.f), W3[o], acc);
        L[(size_t)i * NS + jbase + p * 64 + lane] = acc;
    }
}

// ---------------- Kernel C: per-row sorted top-256 via 16-bit radix ----------------
// top layout is now RANK-LINEAR: top[row*256 + r] = column id of rank-r candidate
// (value-descending, index-ascending on ties). Unfilled slots stay 0xFFFF.
__global__ __launch_bounds__(256) void kC(const float* __restrict__ L,
                                          unsigned short* __restrict__ top) {
    __shared__ int hist[256];
    __shared__ int suff[256];
    __shared__ float cv[1024];
    __shared__ int ci[1024];
    __shared__ int s_cnt, s_B0, s_base, s_B1;
    const int t = threadIdx.x;
    const int row = blockIdx.x;
    const float* __restrict__ Lr = L + (size_t)row * NS;

    top[row * 256 + t] = 0xFFFFu;   // sentinel (degenerate rows -> kD full-fallback)

    hist[t] = 0;
    if (t == 0) s_cnt = 0;
    __syncthreads();

    unsigned ub[6]; float fv[6];
#pragma unroll
    for (int k = 0; k < 6; ++k) {
        const float x = Lr[t + 256 * k];
        fv[k] = x;
        unsigned b = __float_as_uint(x);
        b = (b & 0x80000000u) ? ~b : (b | 0x80000000u);
        ub[k] = b;
        atomicAdd(&hist[b >> 24], 1);
    }
    __syncthreads();

    suff[t] = hist[t];
    __syncthreads();
    for (int off = 1; off < 256; off <<= 1) {
        const int v = (t + off < 256) ? suff[t + off] : 0;
        __syncthreads();
        suff[t] += v;
        __syncthreads();
    }
    if (suff[t] >= 256 && (t == 255 || suff[t + 1] < 256)) {
        s_B0 = t;
        s_base = (t == 255) ? 0 : suff[t + 1];
    }
    __syncthreads();
    const unsigned B0 = (unsigned)s_B0;
    const int base = s_base;

    hist[t] = 0;
    __syncthreads();
#pragma unroll
    for (int k = 0; k < 6; ++k)
        if ((ub[k] >> 24) == B0) atomicAdd(&hist[(ub[k] >> 16) & 255], 1);
    __syncthreads();
    suff[t] = hist[t];
    __syncthreads();
    for (int off = 1; off < 256; off <<= 1) {
        const int v = (t + off < 256) ? suff[t + off] : 0;
        __syncthreads();
        suff[t] += v;
        __syncthreads();
    }
    const int need = 256 - base;
    if (suff[t] >= need && (t == 255 || suff[t + 1] < need)) s_B1 = t;
    __syncthreads();
    const unsigned B1 = (unsigned)s_B1;
    const int m = base + suff[B1];
    if (m > 1024) return;

#pragma unroll
    for (int k = 0; k < 6; ++k) {
        const unsigned hi = ub[k] >> 24;
        const unsigned mid = (ub[k] >> 16) & 255u;
        if (hi > B0 || (hi == B0 && mid >= B1)) {
            const int pos = atomicAdd(&s_cnt, 1);
            cv[pos] = fv[k];
            ci[pos] = t + 256 * k;
        }
    }
    __syncthreads();

    for (int e = t; e < m; e += 256) {
        const float v = cv[e]; const int id = ci[e];
        int r = 0;
        for (int s2 = 0; s2 < m; ++s2) {
            const float vs = cv[s2];
            if (vs > v || (vs == v && ci[s2] < id)) ++r;
        }
        if (r < 256) top[row * 256 + r] = (unsigned short)id;
    }
}

// ---------------- Kernel D: batched greedy, register-resident resolution ----------
// 24 batches of 64 rows. Per batch:
//   scan: lane i prefilters the first 8 currently-unused candidates of row g+i
//         from its rank-ordered top-256 list into 8 registers (memory latency is
//         amortized across 64 rows in parallel, off the serial chain).
//   resolve: 64 sequential steps, PURE register ops on the critical path:
//         j = readlane(front, i); every lane kills slot==j (candidates within a
//         row are distinct -> at most one slot matches) and recomputes front only
//         if its front was consumed. front==0xFFFF at a lane's turn -> exact
//         full-row masked-argmax fallback (rare; preserves reference semantics).
__global__ __launch_bounds__(64) void kD(const float* __restrict__ L,
                                         const unsigned short* __restrict__ top,
                                         int* __restrict__ assign) {
    __shared__ unsigned char used_s[NS];
    __shared__ unsigned short assign_s[NS];
    const int lane = threadIdx.x;
    for (int k = lane; k < NS; k += 64) used_s[k] = 0;
    __syncthreads();

    for (int g = 0; g < NS; g += 64) {
        // ---- prefilter scan for rows g..g+63 (lane i <-> row g+i) ----
        const uint4* __restrict__ rowp =
            (const uint4*)top + (size_t)(g + lane) * 32;   // 32 x uint4 = 256 ushorts
        unsigned c0 = 0xFFFFu, c1 = 0xFFFFu, c2 = 0xFFFFu, c3 = 0xFFFFu,
                 c4 = 0xFFFFu, c5 = 0xFFFFu, c6 = 0xFFFFu, c7 = 0xFFFFu;
        int cnt = 0;
        uint4 q0 = rowp[0];          // 2-deep load pipeline hides L2/L3 latency
        uint4 q1 = rowp[1];
        for (int ch = 0; ch < 32; ++ch) {
            const uint4 cur = q0;
            q0 = q1;
            if (ch < 30) q1 = rowp[ch + 2];

            unsigned cc[8];
            cc[0] = cur.x & 0xFFFFu; cc[1] = cur.x >> 16;
            cc[2] = cur.y & 0xFFFFu; cc[3] = cur.y >> 16;
            cc[4] = cur.z & 0xFFFFu; cc[5] = cur.z >> 16;
            cc[6] = cur.w & 0xFFFFu; cc[7] = cur.w >> 16;
            int uu[8];
#pragma unroll
            for (int t2 = 0; t2 < 8; ++t2)
                uu[t2] = used_s[cc[t2] < NS ? (int)cc[t2] : 0];
#pragma unroll
            for (int t2 = 0; t2 < 8; ++t2) {
                const bool take = (cc[t2] < NS) && (uu[t2] == 0) && (cnt < 8);
                const int sel = take ? cnt : 8;
                c0 = (sel == 0) ? cc[t2] : c0;
                c1 = (sel == 1) ? cc[t2] : c1;
                c2 = (sel == 2) ? cc[t2] : c2;
                c3 = (sel == 3) ? cc[t2] : c3;
                c4 = (sel == 4) ? cc[t2] : c4;
                c5 = (sel == 5) ? cc[t2] : c5;
                c6 = (sel == 6) ? cc[t2] : c6;
                c7 = (sel == 7) ? cc[t2] : c7;
                cnt += (int)take;
            }
            if (__all(cnt >= 8)) break;
        }
        unsigned front = c0;

        // ---- sequential resolution: no memory reads on the common path ----
#pragma unroll 1
        for (int i = 0; i < 64; ++i) {
            unsigned j = (unsigned)__builtin_amdgcn_readlane((int)front, i);
            const int row = g + i;
            if (j >= (unsigned)NS) {
                // full masked argmax over row (exact reference semantics)
                const float* __restrict__ Lr = L + (size_t)row * NS;
                float v[24]; int uf[24];
#pragma unroll
                for (int k = 0; k < 24; ++k) v[k] = Lr[lane + (k << 6)];
#pragma unroll
                for (int k = 0; k < 24; ++k) uf[k] = used_s[lane + (k << 6)];
                float bv = -FLT_MAX; int bi = NS;
#pragma unroll
                for (int k = 0; k < 24; ++k) {
                    const int col = lane + (k << 6);
                    if (uf[k] == 0 && (v[k] > bv || (v[k] == bv && col < bi))) {
                        bv = v[k]; bi = col;
                    }
                }
#pragma unroll
                for (int o = 32; o >= 1; o >>= 1) {
                    const float ov = __shfl_xor(bv, o);
                    const int oi = __shfl_xor(bi, o);
                    if (ov > bv || (ov == bv && oi < bi)) { bv = ov; bi = oi; }
                }
                j = (unsigned)bi;
            }
            if (lane == 0) { used_s[j] = 1; assign_s[row] = (unsigned short)j; }
            // consume j from every lane's candidate list (<=1 slot can match)
            const bool dirty = (front == j) && (lane != i);
            c0 = (c0 == j) ? 0xFFFFu : c0;
            c1 = (c1 == j) ? 0xFFFFu : c1;
            c2 = (c2 == j) ? 0xFFFFu : c2;
            c3 = (c3 == j) ? 0xFFFFu : c3;
            c4 = (c4 == j) ? 0xFFFFu : c4;
            c5 = (c5 == j) ? 0xFFFFu : c5;
            c6 = (c6 == j) ? 0xFFFFu : c6;
            c7 = (c7 == j) ? 0xFFFFu : c7;
            if (dirty) {
                front = (c0 != 0xFFFFu) ? c0 :
                        (c1 != 0xFFFFu) ? c1 :
                        (c2 != 0xFFFFu) ? c2 :
                        (c3 != 0xFFFFu) ? c3 :
                        (c4 != 0xFFFFu) ? c4 :
                        (c5 != 0xFFFFu) ? c5 :
                        (c6 != 0xFFFFu) ? c6 : c7;
            }
        }
        // used_s/assign_s DS writes are in-order within the wave -> visible to
        // next batch's scan without a barrier.
    }

    for (int k = lane; k < NS; k += 64) assign[k] = (int)assign_s[k];
}

// ---------------- Kernel E: emit [1536][2][64] output ----------------
__global__ __launch_bounds__(128) void kE(const float* __restrict__ sat,
                                          const float* __restrict__ uav,
                                          const int* __restrict__ assign,
                                          float* __restrict__ out) {
    const int i = blockIdx.x;
    const int t = threadIdx.x;
    if (t < 64) out[(size_t)i * 128 + t] = sat[(size_t)i * DD + t];
    else        out[(size_t)i * 128 + t] = uav[(size_t)assign[i] * DD + (t - 64)];
}

extern "C" void kernel_launch(void* const* d_in, const int* in_sizes, int n_in,
                              void* d_out, int out_size, void* d_ws, size_t ws_size,
                              hipStream_t stream) {
    const float* sat = (const float*)d_in[0];
    const float* uav = (const float*)d_in[1];
    const float* W1  = (const float*)d_in[2];
    const float* b1  = (const float*)d_in[3];
    const float* W2  = (const float*)d_in[4];
    const float* b2  = (const float*)d_in[5];
    const float* W3  = (const float*)d_in[6];
    // d_in[7] = b3: sigmoid(x+b3) monotone in x — argmax unchanged.

    float* ws = (float*)d_ws;
    float* A   = ws + OFF_A;
    float* C2  = ws + OFF_C2;
    float* L   = ws + OFF_L;
    int* assign = (int*)(ws + OFF_AS);
    unsigned short* top = (unsigned short*)(ws + OFF_A);  // aliases A/C2 (dead after kB)

    hipLaunchKernelGGL(kA, dim3(NS), dim3(64), 0, stream, sat, uav, W1, b1, A, C2);
    hipLaunchKernelGGL(kB, dim3(NS / 4, NS / 256), dim3(256), 0, stream,
                       A, C2, W2, b2, W3, L);
    hipLaunchKernelGGL(kC, dim3(NS), dim3(256), 0, stream, L, top);
    hipLaunchKernelGGL(kD, dim3(1), dim3(64), 0, stream, L, top, assign);
    hipLaunchKernelGGL(kE, dim3(NS), dim3(128), 0, stream, sat, uav, assign,
                       (float*)d_out);
}

// Round 3
// 1045.765 us; speedup vs baseline: 1.5253x; 1.5253x over previous
//
#include <hip/hip_runtime.h>
#include <float.h>

#define NS 1536
#define DD 64

// ws layout (float elements)
static const size_t OFF_A  = 0;                          // A = h_sat + b1: [1536][64]
static const size_t OFF_C2 = 98304;                      // C2 = h_uav transposed [16][1536][4]
static const size_t OFF_L  = 196608;                     // logits [1536][1536]
static const size_t OFF_AS = 196608 + (size_t)NS * NS;   // int assign [1536]
// top_idx (ushort, 1536*256 = 786432 B) ALIASES the A/C2 region (dead after kB).

// ---------------- Kernel A: first-layer projections ----------------
__global__ __launch_bounds__(64) void kA(const float* __restrict__ sat,
                                         const float* __restrict__ uav,
                                         const float* __restrict__ W1,
                                         const float* __restrict__ b1,
                                         float* __restrict__ A,
                                         float* __restrict__ C2) {
    const int row = blockIdx.x;
    const int d = threadIdx.x;
    float accA = b1[d];
    float accC = 0.f;
    const float* __restrict__ satr = sat + row * DD;
    const float* __restrict__ uavr = uav + row * DD;
#pragma unroll 8
    for (int k = 0; k < DD; ++k) {
        accA = fmaf(satr[k], W1[k * DD + d], accA);
        accC = fmaf(uavr[k], W1[(DD + k) * DD + d], accC);
    }
    A[row * DD + d] = accA;
    C2[((size_t)(d >> 2) * NS + row) * 4 + (d & 3)] = accC;
}

// ---------------- Kernel B: all-pairs logits ----------------
__global__ __launch_bounds__(256) void kB(const float* __restrict__ A,
                                          const float* __restrict__ C2,
                                          const float* __restrict__ W2,
                                          const float* __restrict__ b2,
                                          const float* __restrict__ W3,
                                          float* __restrict__ L) {
    const int lane = threadIdx.x & 63;
    const int wave = threadIdx.x >> 6;
    const int i = __builtin_amdgcn_readfirstlane(blockIdx.x * 4 + wave);
    const int jbase = blockIdx.y * 256;
    const float* __restrict__ Ar = A + (size_t)i * DD;

    float u[4][32];
#pragma unroll
    for (int o = 0; o < 32; ++o) {
        const float b = b2[o];
        u[0][o] = b; u[1][o] = b; u[2][o] = b; u[3][o] = b;
    }

    const float4* __restrict__ C2v = (const float4*)C2;

    for (int d4 = 0; d4 < 16; ++d4) {
        float c[4][4];
#pragma unroll
        for (int p = 0; p < 4; ++p) {
            const float4 t = C2v[(size_t)d4 * NS + jbase + p * 64 + lane];
            c[p][0] = t.x; c[p][1] = t.y; c[p][2] = t.z; c[p][3] = t.w;
        }
#pragma unroll
        for (int dd = 0; dd < 4; ++dd) {
            const float a = Ar[d4 * 4 + dd];
            const float v0 = fmaxf(a + c[0][dd], 0.f);
            const float v1 = fmaxf(a + c[1][dd], 0.f);
            const float v2 = fmaxf(a + c[2][dd], 0.f);
            const float v3 = fmaxf(a + c[3][dd], 0.f);
            const float* __restrict__ w2r = W2 + (d4 * 4 + dd) * 32;
#pragma unroll
            for (int o = 0; o < 32; ++o) {
                const float w = w2r[o];
                u[0][o] = fmaf(v0, w, u[0][o]);
                u[1][o] = fmaf(v1, w, u[1][o]);
                u[2][o] = fmaf(v2, w, u[2][o]);
                u[3][o] = fmaf(v3, w, u[3][o]);
            }
        }
    }

#pragma unroll
    for (int p = 0; p < 4; ++p) {
        float acc = 0.f;
#pragma unroll
        for (int o = 0; o < 32; ++o)
            acc = fmaf(fmaxf(u[p][o], 0.f), W3[o], acc);
        L[(size_t)i * NS + jbase + p * 64 + lane] = acc;
    }
}

// ---------------- Kernel C: per-row sorted top-256 via 16-bit radix ----------------
// Swizzled layout: rank r lives at top[row*256 + (r&63)*4 + (r>>6)] so kD's
// uint2-per-lane read gives lane l ranks {l, l+64, l+128, l+192}.
__global__ __launch_bounds__(256) void kC(const float* __restrict__ L,
                                          unsigned short* __restrict__ top) {
    __shared__ int hist[256];
    __shared__ int suff[256];
    __shared__ float cv[1024];
    __shared__ int ci[1024];
    __shared__ int s_cnt, s_B0, s_base, s_B1;
    const int t = threadIdx.x;
    const int row = blockIdx.x;
    const float* __restrict__ Lr = L + (size_t)row * NS;

    top[row * 256 + t] = 0xFFFFu;   // sentinel (degenerate rows -> kD fallback)

    hist[t] = 0;
    if (t == 0) s_cnt = 0;
    __syncthreads();

    unsigned ub[6]; float fv[6];
#pragma unroll
    for (int k = 0; k < 6; ++k) {
        const float x = Lr[t + 256 * k];
        fv[k] = x;
        unsigned b = __float_as_uint(x);
        b = (b & 0x80000000u) ? ~b : (b | 0x80000000u);
        ub[k] = b;
        atomicAdd(&hist[b >> 24], 1);
    }
    __syncthreads();

    suff[t] = hist[t];
    __syncthreads();
    for (int off = 1; off < 256; off <<= 1) {
        const int v = (t + off < 256) ? suff[t + off] : 0;
        __syncthreads();
        suff[t] += v;
        __syncthreads();
    }
    if (suff[t] >= 256 && (t == 255 || suff[t + 1] < 256)) {
        s_B0 = t;
        s_base = (t == 255) ? 0 : suff[t + 1];
    }
    __syncthreads();
    const unsigned B0 = (unsigned)s_B0;
    const int base = s_base;

    hist[t] = 0;
    __syncthreads();
#pragma unroll
    for (int k = 0; k < 6; ++k)
        if ((ub[k] >> 24) == B0) atomicAdd(&hist[(ub[k] >> 16) & 255], 1);
    __syncthreads();
    suff[t] = hist[t];
    __syncthreads();
    for (int off = 1; off < 256; off <<= 1) {
        const int v = (t + off < 256) ? suff[t + off] : 0;
        __syncthreads();
        suff[t] += v;
        __syncthreads();
    }
    const int need = 256 - base;
    if (suff[t] >= need && (t == 255 || suff[t + 1] < need)) s_B1 = t;
    __syncthreads();
    const unsigned B1 = (unsigned)s_B1;
    const int m = base + suff[B1];
    if (m > 1024) return;

#pragma unroll
    for (int k = 0; k < 6; ++k) {
        const unsigned hi = ub[k] >> 24;
        const unsigned mid = (ub[k] >> 16) & 255u;
        if (hi > B0 || (hi == B0 && mid >= B1)) {
            const int pos = atomicAdd(&s_cnt, 1);
            cv[pos] = fv[k];
            ci[pos] = t + 256 * k;
        }
    }
    __syncthreads();

    for (int e = t; e < m; e += 256) {
        const float v = cv[e]; const int id = ci[e];
        int r = 0;
        for (int s2 = 0; s2 < m; ++s2) {
            const float vs = cv[s2];
            if (vs > v || (vs == v && ci[s2] < id)) ++r;
        }
        if (r < 256) top[row * 256 + (r & 63) * 4 + (r >> 6)] = (unsigned short)id;
    }
}

// ---------------- Kernel D: sequential greedy (single wave) ----------------
// Round-0 pipelined ballot structure (proven 1013us), with ONE change: the
// exhausted-top-256 fallback is now an argmax over a compacted unused-uav
// list U_s (rebuilt every 64 rows). Fallbacks occur on LATE rows where
// mU = 1536-i is small -> one ~8-wide gather round (~1k cy) instead of 24
// serial row loads (~2.4-12k cy). Exact: U_s is a superset of the current
// unused set (stale entries filtered via live used_s), argmax tiebreak = min
// index, sigmoid monotone.
__global__ __launch_bounds__(64) void kD(const float* __restrict__ L,
                                         const unsigned short* __restrict__ top,
                                         int* __restrict__ assign) {
    __shared__ int used_s[NS];
    __shared__ int assign_s[NS];
    __shared__ unsigned short U_s[NS];
    const int lane = threadIdx.x;
    for (int k = lane; k < NS; k += 64) used_s[k] = 0;
    __syncthreads();

    const uint2* __restrict__ T = (const uint2*)top;   // T[row*64 + lane]

    uint2 buf[16];           // rows g..g+15
#pragma unroll
    for (int k = 0; k < 16; ++k) buf[k] = T[k * 64 + lane];

    int f0 = 0, f1 = 0, f2 = 0, f3 = 0;   // row-0 flags: nothing used yet
    int jprev = -1;
    int mU = NS;

    for (int g = 0; g < NS; g += 8) {
        // ---- rebuild compact unused list every 64 rows ----
        if ((g & 63) == 0) {
            int fl[24];
#pragma unroll
            for (int k = 0; k < 24; ++k) fl[k] = used_s[lane + (k << 6)];
            int cnt = 0;
#pragma unroll
            for (int k = 0; k < 24; ++k) cnt += (fl[k] == 0);
            int incl = cnt;
#pragma unroll
            for (int o = 1; o < 64; o <<= 1) {
                const int v = __shfl_up(incl, o);
                if (lane >= o) incl += v;
            }
            int pos = incl - cnt;   // exclusive prefix
#pragma unroll
            for (int k = 0; k < 24; ++k) {
                if (fl[k] == 0) { U_s[pos] = (unsigned short)(lane + (k << 6)); ++pos; }
            }
            mU = __builtin_amdgcn_readlane(incl, 63);
            // single wave: LDS ops in-order, no barrier needed
        }

        // issue loads for rows g+16..g+23 (consumed 2 groups from now)
        uint2 nb[8];
#pragma unroll
        for (int k = 0; k < 8; ++k) {
            int r = g + 16 + k;
            r = (r < NS) ? r : (NS - 1);
            nb[k] = T[r * 64 + lane];
        }

#pragma unroll
        for (int q = 0; q < 8; ++q) {
            const int i = g + q;

            // prefetch used-flags for row i+1 (candidates resident in buf[q+1])
            const uint2 pn = buf[q + 1];
            const int n0 = (int)(pn.x & 0xFFFFu), n1 = (int)(pn.x >> 16);
            const int n2 = (int)(pn.y & 0xFFFFu), n3 = (int)(pn.y >> 16);
            const int g0 = used_s[n0 < NS ? n0 : 0];
            const int g1 = used_s[n1 < NS ? n1 : 0];
            const int g2 = used_s[n2 < NS ? n2 : 0];
            const int g3 = used_s[n3 < NS ? n3 : 0];

            const uint2 pc = buf[q];
            const int c0 = (int)(pc.x & 0xFFFFu), c1 = (int)(pc.x >> 16);
            const int c2 = (int)(pc.y & 0xFFFFu), c3 = (int)(pc.y >> 16);
            const bool a0 = (c0 < NS) && (f0 == 0) && (c0 != jprev);
            const bool a1 = (c1 < NS) && (f1 == 0) && (c1 != jprev);
            const bool a2 = (c2 < NS) && (f2 == 0) && (c2 != jprev);
            const bool a3 = (c3 < NS) && (f3 == 0) && (c3 != jprev);
            const unsigned long long b0 = __ballot(a0);
            const unsigned long long b1 = __ballot(a1);
            const unsigned long long b2 = __ballot(a2);
            const unsigned long long b3 = __ballot(a3);

            int j;
            if (b0)      j = __builtin_amdgcn_readlane(c0, __ffsll(b0) - 1);
            else if (b1) j = __builtin_amdgcn_readlane(c1, __ffsll(b1) - 1);
            else if (b2) j = __builtin_amdgcn_readlane(c2, __ffsll(b2) - 1);
            else if (b3) j = __builtin_amdgcn_readlane(c3, __ffsll(b3) - 1);
            else {
                // argmax over compact unused list (exact reference semantics)
                const float* __restrict__ Lr = L + (size_t)i * NS;
                float bv = -FLT_MAX; int bi = NS;
                for (int kbase = 0; kbase < mU; kbase += 512) {
                    int idx[8]; int flc[8]; float vv[8];
#pragma unroll
                    for (int c = 0; c < 8; ++c) {
                        const int k = kbase + lane + (c << 6);
                        idx[c] = (k < mU) ? (int)U_s[k] : 0;
                    }
#pragma unroll
                    for (int c = 0; c < 8; ++c) flc[c] = used_s[idx[c]];
#pragma unroll
                    for (int c = 0; c < 8; ++c) vv[c] = Lr[idx[c]];
#pragma unroll
                    for (int c = 0; c < 8; ++c) {
                        const int k = kbase + lane + (c << 6);
                        if (k < mU && flc[c] == 0 &&
                            (vv[c] > bv || (vv[c] == bv && idx[c] < bi))) {
                            bv = vv[c]; bi = idx[c];
                        }
                    }
                }
#pragma unroll
                for (int o = 32; o >= 1; o >>= 1) {
                    const float ov = __shfl_xor(bv, o);
                    const int oi = __shfl_xor(bi, o);
                    if (ov > bv || (ov == bv && oi < bi)) { bv = ov; bi = oi; }
                }
                j = bi;
            }
            if (lane == 0) { used_s[j] = 1; assign_s[i] = j; }
            jprev = j;
            f0 = g0; f1 = g1; f2 = g2; f3 = g3;
        }

        // rotate: waits only for loads issued ~8 rows ago (fully landed)
#pragma unroll
        for (int k = 0; k < 8; ++k) buf[k] = buf[k + 8];
#pragma unroll
        for (int k = 0; k < 8; ++k) buf[k + 8] = nb[k];
    }

    for (int k = lane; k < NS; k += 64) assign[k] = assign_s[k];
}

// ---------------- Kernel E: emit [1536][2][64] output ----------------
__global__ __launch_bounds__(128) void kE(const float* __restrict__ sat,
                                          const float* __restrict__ uav,
                                          const int* __restrict__ assign,
                                          float* __restrict__ out) {
    const int i = blockIdx.x;
    const int t = threadIdx.x;
    if (t < 64) out[(size_t)i * 128 + t] = sat[(size_t)i * DD + t];
    else        out[(size_t)i * 128 + t] = uav[(size_t)assign[i] * DD + (t - 64)];
}

extern "C" void kernel_launch(void* const* d_in, const int* in_sizes, int n_in,
                              void* d_out, int out_size, void* d_ws, size_t ws_size,
                              hipStream_t stream) {
    const float* sat = (const float*)d_in[0];
    const float* uav = (const float*)d_in[1];
    const float* W1  = (const float*)d_in[2];
    const float* b1  = (const float*)d_in[3];
    const float* W2  = (const float*)d_in[4];
    const float* b2  = (const float*)d_in[5];
    const float* W3  = (const float*)d_in[6];
    // d_in[7] = b3: sigmoid(x+b3) monotone in x — argmax unchanged.

    float* ws = (float*)d_ws;
    float* A   = ws + OFF_A;
    float* C2  = ws + OFF_C2;
    float* L   = ws + OFF_L;
    int* assign = (int*)(ws + OFF_AS);
    unsigned short* top = (unsigned short*)(ws + OFF_A);  // aliases A/C2 (dead after kB)

    hipLaunchKernelGGL(kA, dim3(NS), dim3(64), 0, stream, sat, uav, W1, b1, A, C2);
    hipLaunchKernelGGL(kB, dim3(NS / 4, NS / 256), dim3(256), 0, stream,
                       A, C2, W2, b2, W3, L);
    hipLaunchKernelGGL(kC, dim3(NS), dim3(256), 0, stream, L, top);
    hipLaunchKernelGGL(kD, dim3(1), dim3(64), 0, stream, L, top, assign);
    hipLaunchKernelGGL(kE, dim3(NS), dim3(128), 0, stream, sat, uav, assign,
                       (float*)d_out);
}